// Round 1
// baseline (690.693 us; speedup 1.0000x reference)
//
#include <hip/hip_runtime.h>
#include <stdint.h>

#define HH 80
#define WW 80
#define CC 64
#define BB 32
#define NDIAG (HH + WW - 1)   // 159
#define SLICE (HH * WW * CC)  // 409600 f16 per (dir,b) scratch slice
#define NCW 5                 // compute waves (one 16-cell tile each)
#define NTHREADS 320          // 5 waves, all identical role

typedef _Float16 f16;
typedef _Float16 f16x8 __attribute__((ext_vector_type(8)));
typedef _Float16 f16x4 __attribute__((ext_vector_type(4)));
typedef float floatx4 __attribute__((ext_vector_type(4)));

struct GPtrs { const float* p[8]; };

// ---------------------------------------------------------------------------
// Main kernel: 128 blocks x 320 threads (5 waves, no io waves, no x LDS ring).
// Per diagonal interval, each wave:
//   - seeds MFMA C with f32 x prefetched 2 diagonals ahead (regs, depth-2:
//     even a conservative vmcnt drain only costs lat - ~1 interval)
//   - reads prev-diag h from hbuf (LDS), runs two independent 2-deep MFMA
//     chains (Gv and Gh), adds, relu, packs f16
//   - ds_writes h for the next diagonal AND global-stores it to scratch
//     straight from registers (fire-and-forget; quads give contiguous 32B
//     runs per cell, L2 write-combines the 4 cb stores into full lines)
//   - issues next x prefetch LAST, then lgkmcnt(0)-only raw barrier
// The only vmem wait on the barrier-to-barrier path is the depth-2-covered
// x seed; no wave ever waits on a just-issued load.
// ---------------------------------------------------------------------------
__global__ __launch_bounds__(NTHREADS, 1) void dag_kernel(const float* __restrict__ x,
                                                          GPtrs g,
                                                          f16* __restrict__ scratch) {
  const int blk = blockIdx.x;   // 0..127
  const int dir = blk >> 5;     // 0:SE 1:NE 2:NW 3:SW
  const int b   = blk & 31;
  const int tid = threadIdx.x;
  const int wv   = tid >> 6;    // 0..4
  const int lane = tid & 63;
  const int l15  = lane & 15;   // cell-in-tile (MFMA n / C-D col)
  const int quad = lane >> 4;   // k-quad / C-D row-quad
  const int cq   = quad * 4;

  const bool fi      = (dir == 1) || (dir == 2);  // flip i
  const bool fj      = (dir == 2) || (dir == 3);  // flip j
  const bool do_relu = (dir != 3);                // SW scan has no ReLU
  const float* __restrict__ gv = g.p[2 * dir];
  const float* __restrict__ gh = g.p[2 * dir + 1];

  // h state: [parity][s][c]; s=i'+1, s=0 zero guard, s=81 top guard. 144B rows.
  __align__(16) __shared__ f16 hbuf[2][HH + 2][CC + 8];   // 23,616 B

  {
    f16x8 z = {};
    f16x8* hb = (f16x8*)&hbuf[0][0][0];
    for (int idx = tid; idx < (2 * (HH + 2) * (CC + 8)) / 8; idx += NTHREADS)
      hb[idx] = z;
  }

  const float* const xb_ = x + (size_t)b * (CC * HH * WW);
  f16* const sbase = scratch + (size_t)blk * SLICE;

  // gamma A fragments: A[m][k], m = cb*16 + l15, k = half*32 + quad*8 + jj
  f16x8 Av[4][2], Ah[4][2];
#pragma unroll
  for (int cb = 0; cb < 4; ++cb) {
    const int row = cb * 16 + l15;
    const float* pv = gv + row * CC;
    const float* ph = gh + row * CC;
#pragma unroll
    for (int jj = 0; jj < 8; ++jj) {
      Av[cb][0][jj] = (f16)pv[quad * 8 + jj];
      Av[cb][1][jj] = (f16)pv[32 + quad * 8 + jj];
      Ah[cb][0][jj] = (f16)ph[quad * 8 + jj];
      Ah[cb][1][jj] = (f16)ph[32 + quad * 8 + jj];
    }
  }

  // x prefetch: X[cb][r] = x[b][cb*16+cq+r][cell(l15) of diag dd], f32 direct.
  // Lanes l15 -> consecutive j -> 64B-contiguous per (cb,r,quad) load.
  floatx4 XA[4], XB[4];
  auto prefetch = [&](int dd, floatx4 (&X)[4]) {
    const int lo2 = max(0, dd - (WW - 1));
    const int hi2 = min(dd, HH - 1);
    const int ipc = min(lo2 + wv * 16 + l15, hi2);  // clamped: dup loads benign
    const int jp2 = dd - ipc;
    const int io2 = fi ? (HH - 1 - ipc) : ipc;
    const int jo2 = fj ? (WW - 1 - jp2) : jp2;
    const float* xp = xb_ + (io2 * WW + jo2);
#pragma unroll
    for (int cb = 0; cb < 4; ++cb)
#pragma unroll
      for (int r = 0; r < 4; ++r)
        X[cb][r] = xp[(cb * 16 + cq + r) * (HH * WW)];
  };

  prefetch(0, XA);
  prefetch(1, XB);
  __syncthreads();  // one-time full drain: hbuf zeros (+ prologue loads)

  auto step = [&](int d, int par, floatx4 (&X)[4]) {
    const int ilo = max(0, d - (WW - 1));
    const int ihi = min(d, HH - 1);
    const int ntiles = ((ihi - ilo) >> 4) + 1;
    if (wv < ntiles) {                     // wave-uniform
      const int ip  = ilo + wv * 16 + l15;
      const int ipa = min(ip, ihi);        // clamped for addresses
      const int su  = min(ip, HH + 1);     // up   (i'-1,j') -> s=i'
      const int sl  = min(ip + 1, HH + 1); // left (i',j'-1) -> s=i'+1
      const f16x8 bu0 = *(const f16x8*)&hbuf[par ^ 1][su][quad * 8];
      const f16x8 bu1 = *(const f16x8*)&hbuf[par ^ 1][su][32 + quad * 8];
      const f16x8 bl0 = *(const f16x8*)&hbuf[par ^ 1][sl][quad * 8];
      const f16x8 bl1 = *(const f16x8*)&hbuf[par ^ 1][sl][32 + quad * 8];
      const bool ok = (ip <= ihi);
      const int jp  = d - ipa;
      const int io1 = fi ? (HH - 1 - ipa) : ipa;
      const int jo1 = fj ? (WW - 1 - jp) : jp;
      f16* const so = sbase + ((io1 * WW + jo1) << 6);
#pragma unroll
      for (int cb = 0; cb < 4; ++cb) {
        floatx4 a1 = X[cb];                       // seed C with f32 x (free)
        floatx4 a2 = {0.f, 0.f, 0.f, 0.f};
        // two independent 2-deep chains (Gv | Gh) -> shorter latency path
        a1 = __builtin_amdgcn_mfma_f32_16x16x32_f16(Av[cb][0], bu0, a1, 0, 0, 0);
        a2 = __builtin_amdgcn_mfma_f32_16x16x32_f16(Ah[cb][0], bl0, a2, 0, 0, 0);
        a1 = __builtin_amdgcn_mfma_f32_16x16x32_f16(Av[cb][1], bu1, a1, 0, 0, 0);
        a2 = __builtin_amdgcn_mfma_f32_16x16x32_f16(Ah[cb][1], bl1, a2, 0, 0, 0);
        float h0 = a1[0] + a2[0], h1 = a1[1] + a2[1];
        float h2 = a1[2] + a2[2], h3 = a1[3] + a2[3];
        if (do_relu) {
          h0 = fmaxf(h0, 0.f); h1 = fmaxf(h1, 0.f);
          h2 = fmaxf(h2, 0.f); h3 = fmaxf(h3, 0.f);
        }
        f16x4 hw;
        hw[0] = (f16)h0; hw[1] = (f16)h1; hw[2] = (f16)h2; hw[3] = (f16)h3;
        if (ok) {
          *(f16x4*)&hbuf[par][ip + 1][cb * 16 + cq] = hw;   // for next diag
          *(f16x4*)(so + cb * 16 + cq) = hw;                // fire-and-forget
        }
      }
    }
    // issue next prefetch LAST (unconditional: waves may activate later)
    prefetch(min(d + 2, NDIAG - 1), X);
    // Raw barrier: drain LDS only (lgkmcnt(0)); vmem stays in flight.
    __builtin_amdgcn_s_waitcnt(0xC07F);  // vmcnt(63) expcnt(7) lgkmcnt(0)
    __builtin_amdgcn_s_barrier();
  };

  for (int d = 0; d < NDIAG - 1; d += 2) {  // parity as literal -> folded addrs
    step(d, 0, XA);
    step(d + 1, 1, XB);
  }
  step(NDIAG - 1, 0, XA);  // 158 is even
}

// ---------------------------------------------------------------------------
// Reduce: out[b][c][i][j] = sum over 4 dirs of scratch[dir][b][i][j][c].
// ---------------------------------------------------------------------------
__global__ __launch_bounds__(256) void reduce_kernel(const f16* __restrict__ s,
                                                     float* __restrict__ out) {
  const int bi = blockIdx.x;            // b*HH + i
  const int b = bi / HH, i = bi - b * HH;
  __shared__ float tile[WW][CC + 1];    // [j][c], stride 65
  const size_t dstride = (size_t)BB * SLICE;
  const f16* p = s + (size_t)b * SLICE + (size_t)i * (WW * CC);
  for (int idx = threadIdx.x; idx < (WW * CC) / 8; idx += 256) {  // 640
    const int j = idx >> 3, c8 = (idx & 7) * 8;
    const size_t off = (size_t)j * CC + c8;
    const f16x8 a0 = *(const f16x8*)(p + off);
    const f16x8 a1 = *(const f16x8*)(p + off + dstride);
    const f16x8 a2 = *(const f16x8*)(p + off + 2 * dstride);
    const f16x8 a3 = *(const f16x8*)(p + off + 3 * dstride);
#pragma unroll
    for (int k = 0; k < 8; ++k)
      tile[j][c8 + k] = (float)a0[k] + (float)a1[k] + (float)a2[k] + (float)a3[k];
  }
  __syncthreads();
  float* op = out + ((size_t)(b * CC) * HH + i) * WW;  // + c*(H*W) + j
  const int c  = threadIdx.x >> 2;        // 0..63
  const int jb = (threadIdx.x & 3) * 4;   // 0,4,8,12
#pragma unroll
  for (int k = 0; k < 5; ++k) {
    const int j0 = jb + k * 16;
    floatx4 v;
    v[0] = tile[j0 + 0][c];
    v[1] = tile[j0 + 1][c];
    v[2] = tile[j0 + 2][c];
    v[3] = tile[j0 + 3][c];
    *(floatx4*)(op + (size_t)c * (HH * WW) + j0) = v;  // 64B contiguous per 4 lanes
  }
}

// ---------------------------------------------------------------------------
extern "C" void kernel_launch(void* const* d_in, const int* in_sizes, int n_in,
                              void* d_out, int out_size, void* d_ws, size_t ws_size,
                              hipStream_t stream) {
  const float* x = (const float*)d_in[0];
  GPtrs g;
  for (int k = 0; k < 8; ++k) g.p[k] = (const float*)d_in[k + 1];  // g1,g2,g4,g5,g7,g8,g10,g11
  f16* scratch = (f16*)d_ws;                    // 104.9 MB

  dag_kernel<<<4 * BB, NTHREADS, 0, stream>>>(x, g, scratch);
  reduce_kernel<<<BB * HH, 256, 0, stream>>>((const f16*)scratch, (float*)d_out);
}

// Round 2
// 302.805 us; speedup vs baseline: 2.2810x; 2.2810x over previous
//
#include <hip/hip_runtime.h>
#include <stdint.h>

#define HH 80
#define WW 80
#define CC 64
#define BB 32
#define NDIAG (HH + WW - 1)   // 159
#define SLICE (HH * WW * CC)  // 409600 f16 per (dir,b) scratch slice
#define NCW 5                 // compute waves (one 16-cell tile each)
#define NTHREADS 320          // 5 waves, all identical role

typedef _Float16 f16;
typedef _Float16 f16x8 __attribute__((ext_vector_type(8)));
typedef _Float16 f16x4 __attribute__((ext_vector_type(4)));
typedef float floatx4 __attribute__((ext_vector_type(4)));

struct GPtrs { const float* p[8]; };

// ---------------------------------------------------------------------------
// Pre-pass: x[b][c][i][j] (f32) -> xT[((b*H+i)*W+j)*C + c] (f16).
// One cell's 64 channels = one contiguous 128B line (this is what makes the
// dag kernel's diagonal x reads coalesced; round-1's direct-f32 read was a
// 29x fetch amplification).
// ---------------------------------------------------------------------------
__global__ __launch_bounds__(256) void xpose_kernel(const float* __restrict__ x,
                                                    f16* __restrict__ xT) {
  const int bi = blockIdx.x;            // b*HH + i
  const int b = bi / HH, i = bi - b * HH;
  __shared__ float tile[WW][CC + 1];    // [j][c], stride 65
  const float* xp = x + ((size_t)(b * CC) * HH + i) * WW;  // + c*(H*W) + j
  for (int idx = threadIdx.x; idx < CC * WW; idx += 256) {
    const int c = idx / WW, j = idx - c * WW;   // consecutive j -> coalesced reads
    tile[j][c] = xp[(size_t)c * (HH * WW) + j];
  }
  __syncthreads();
  f16* op = xT + (size_t)(b * HH + i) * WW * CC;
  for (int idx = threadIdx.x; idx < (WW * CC) / 4; idx += 256) {
    const int j = idx >> 4, m = idx & 15;       // 16 lanes cover one j
    f16x4 v;
    v[0] = (f16)tile[j][m * 4 + 0];
    v[1] = (f16)tile[j][m * 4 + 1];
    v[2] = (f16)tile[j][m * 4 + 2];
    v[3] = (f16)tile[j][m * 4 + 3];
    *(f16x4*)(op + j * CC + m * 4) = v;         // 128B contiguous per 16 lanes
  }
}

// ---------------------------------------------------------------------------
// Main kernel: 128 blocks x 320 threads (5 waves, no io waves, no x LDS ring).
// Per diagonal interval, each wave:
//   - seeds MFMA C with x read from xT (f16, cell-contiguous) prefetched 2
//     diagonals ahead into registers (4 x 8B coalesced loads per thread)
//   - reads prev-diag h from hbuf (LDS), runs two independent 2-deep MFMA
//     chains (Gv | Gh), adds, relu, packs f16
//   - ds_writes h for the next diagonal AND global-stores it to scratch
//     straight from registers (fire-and-forget)
//   - issues next x prefetch LAST, then lgkmcnt(0)-only raw barrier
// No wave ever waits on a just-issued vmem op on the barrier-to-barrier path.
// ---------------------------------------------------------------------------
__global__ __launch_bounds__(NTHREADS, 1) void dag_kernel(const f16* __restrict__ xT,
                                                          GPtrs g,
                                                          f16* __restrict__ scratch) {
  const int blk = blockIdx.x;   // 0..127
  const int dir = blk >> 5;     // 0:SE 1:NE 2:NW 3:SW
  const int b   = blk & 31;
  const int tid = threadIdx.x;
  const int wv   = tid >> 6;    // 0..4
  const int lane = tid & 63;
  const int l15  = lane & 15;   // cell-in-tile (MFMA n / C-D col)
  const int quad = lane >> 4;   // k-quad / C-D row-quad
  const int cq   = quad * 4;

  const bool fi      = (dir == 1) || (dir == 2);  // flip i
  const bool fj      = (dir == 2) || (dir == 3);  // flip j
  const bool do_relu = (dir != 3);                // SW scan has no ReLU
  const float* __restrict__ gv = g.p[2 * dir];
  const float* __restrict__ gh = g.p[2 * dir + 1];

  // h state: [parity][s][c]; s=i'+1, s=0 zero guard, s=81 top guard. 144B rows.
  __align__(16) __shared__ f16 hbuf[2][HH + 2][CC + 8];   // 23,616 B

  {
    f16x8 z = {};
    f16x8* hb = (f16x8*)&hbuf[0][0][0];
    for (int idx = tid; idx < (2 * (HH + 2) * (CC + 8)) / 8; idx += NTHREADS)
      hb[idx] = z;
  }

  const f16* const xTb = xT + (size_t)b * SLICE;
  f16* const sbase = scratch + (size_t)blk * SLICE;

  // gamma A fragments: A[m][k], m = cb*16 + l15, k = half*32 + quad*8 + jj
  f16x8 Av[4][2], Ah[4][2];
#pragma unroll
  for (int cb = 0; cb < 4; ++cb) {
    const int row = cb * 16 + l15;
    const float* pv = gv + row * CC;
    const float* ph = gh + row * CC;
#pragma unroll
    for (int jj = 0; jj < 8; ++jj) {
      Av[cb][0][jj] = (f16)pv[quad * 8 + jj];
      Av[cb][1][jj] = (f16)pv[32 + quad * 8 + jj];
      Ah[cb][0][jj] = (f16)ph[quad * 8 + jj];
      Ah[cb][1][jj] = (f16)ph[32 + quad * 8 + jj];
    }
  }

  // x prefetch: X[cb] = xT[cell(l15 of diag dd)][cb*16+cq .. +3], f16x4 (8B).
  // A wave's 64 lanes cover 16 cells x 4 quads: per cb, 16 full 32B segments;
  // across cb, each cell's whole 128B line read exactly once per wave.
  f16x4 XA[4], XB[4];
  auto prefetch = [&](int dd, f16x4 (&X)[4]) {
    const int lo2 = max(0, dd - (WW - 1));
    const int hi2 = min(dd, HH - 1);
    const int ipc = min(lo2 + wv * 16 + l15, hi2);  // clamped: dup loads benign
    const int jp2 = dd - ipc;
    const int io2 = fi ? (HH - 1 - ipc) : ipc;
    const int jo2 = fj ? (WW - 1 - jp2) : jp2;
    const f16* xp = xTb + ((io2 * WW + jo2) << 6) + cq;
#pragma unroll
    for (int cb = 0; cb < 4; ++cb)
      X[cb] = *(const f16x4*)(xp + cb * 16);
  };

  prefetch(0, XA);
  prefetch(1, XB);
  __syncthreads();  // one-time full drain: hbuf zeros (+ prologue loads)

  auto step = [&](int d, int par, f16x4 (&X)[4]) {
    const int ilo = max(0, d - (WW - 1));
    const int ihi = min(d, HH - 1);
    const int ntiles = ((ihi - ilo) >> 4) + 1;
    if (wv < ntiles) {                     // wave-uniform
      const int ip  = ilo + wv * 16 + l15;
      const int ipa = min(ip, ihi);        // clamped for addresses
      const int su  = min(ip, HH + 1);     // up   (i'-1,j') -> s=i'
      const int sl  = min(ip + 1, HH + 1); // left (i',j'-1) -> s=i'+1
      const f16x8 bu0 = *(const f16x8*)&hbuf[par ^ 1][su][quad * 8];
      const f16x8 bu1 = *(const f16x8*)&hbuf[par ^ 1][su][32 + quad * 8];
      const f16x8 bl0 = *(const f16x8*)&hbuf[par ^ 1][sl][quad * 8];
      const f16x8 bl1 = *(const f16x8*)&hbuf[par ^ 1][sl][32 + quad * 8];
      const bool ok = (ip <= ihi);
      const int jp  = d - ipa;
      const int io1 = fi ? (HH - 1 - ipa) : ipa;
      const int jo1 = fj ? (WW - 1 - jp) : jp;
      f16* const so = sbase + ((io1 * WW + jo1) << 6);
#pragma unroll
      for (int cb = 0; cb < 4; ++cb) {
        floatx4 a1;
        a1[0] = (float)X[cb][0]; a1[1] = (float)X[cb][1];  // seed C with x
        a1[2] = (float)X[cb][2]; a1[3] = (float)X[cb][3];
        floatx4 a2 = {0.f, 0.f, 0.f, 0.f};
        // two independent 2-deep chains (Gv | Gh) -> shorter latency path
        a1 = __builtin_amdgcn_mfma_f32_16x16x32_f16(Av[cb][0], bu0, a1, 0, 0, 0);
        a2 = __builtin_amdgcn_mfma_f32_16x16x32_f16(Ah[cb][0], bl0, a2, 0, 0, 0);
        a1 = __builtin_amdgcn_mfma_f32_16x16x32_f16(Av[cb][1], bu1, a1, 0, 0, 0);
        a2 = __builtin_amdgcn_mfma_f32_16x16x32_f16(Ah[cb][1], bl1, a2, 0, 0, 0);
        float h0 = a1[0] + a2[0], h1 = a1[1] + a2[1];
        float h2 = a1[2] + a2[2], h3 = a1[3] + a2[3];
        if (do_relu) {
          h0 = fmaxf(h0, 0.f); h1 = fmaxf(h1, 0.f);
          h2 = fmaxf(h2, 0.f); h3 = fmaxf(h3, 0.f);
        }
        f16x4 hw;
        hw[0] = (f16)h0; hw[1] = (f16)h1; hw[2] = (f16)h2; hw[3] = (f16)h3;
        if (ok) {
          *(f16x4*)&hbuf[par][ip + 1][cb * 16 + cq] = hw;   // for next diag
          *(f16x4*)(so + cb * 16 + cq) = hw;                // fire-and-forget
        }
      }
    }
    // issue next prefetch LAST (unconditional: waves may activate later)
    prefetch(min(d + 2, NDIAG - 1), X);
    // Raw barrier: drain LDS only (lgkmcnt(0)); vmem stays in flight.
    __builtin_amdgcn_s_waitcnt(0xC07F);  // vmcnt(63) expcnt(7) lgkmcnt(0)
    __builtin_amdgcn_s_barrier();
  };

  for (int d = 0; d < NDIAG - 1; d += 2) {  // parity as literal -> folded addrs
    step(d, 0, XA);
    step(d + 1, 1, XB);
  }
  step(NDIAG - 1, 0, XA);  // 158 is even
}

// ---------------------------------------------------------------------------
// Reduce: out[b][c][i][j] = sum over 4 dirs of scratch[dir][b][i][j][c].
// ---------------------------------------------------------------------------
__global__ __launch_bounds__(256) void reduce_kernel(const f16* __restrict__ s,
                                                     float* __restrict__ out) {
  const int bi = blockIdx.x;            // b*HH + i
  const int b = bi / HH, i = bi - b * HH;
  __shared__ float tile[WW][CC + 1];    // [j][c], stride 65
  const size_t dstride = (size_t)BB * SLICE;
  const f16* p = s + (size_t)b * SLICE + (size_t)i * (WW * CC);
  for (int idx = threadIdx.x; idx < (WW * CC) / 8; idx += 256) {  // 640
    const int j = idx >> 3, c8 = (idx & 7) * 8;
    const size_t off = (size_t)j * CC + c8;
    const f16x8 a0 = *(const f16x8*)(p + off);
    const f16x8 a1 = *(const f16x8*)(p + off + dstride);
    const f16x8 a2 = *(const f16x8*)(p + off + 2 * dstride);
    const f16x8 a3 = *(const f16x8*)(p + off + 3 * dstride);
#pragma unroll
    for (int k = 0; k < 8; ++k)
      tile[j][c8 + k] = (float)a0[k] + (float)a1[k] + (float)a2[k] + (float)a3[k];
  }
  __syncthreads();
  float* op = out + ((size_t)(b * CC) * HH + i) * WW;  // + c*(H*W) + j
  const int c  = threadIdx.x >> 2;        // 0..63
  const int jb = (threadIdx.x & 3) * 4;   // 0,4,8,12
#pragma unroll
  for (int k = 0; k < 5; ++k) {
    const int j0 = jb + k * 16;
    floatx4 v;
    v[0] = tile[j0 + 0][c];
    v[1] = tile[j0 + 1][c];
    v[2] = tile[j0 + 2][c];
    v[3] = tile[j0 + 3][c];
    *(floatx4*)(op + (size_t)c * (HH * WW) + j0) = v;  // 64B contiguous per 4 lanes
  }
}

// ---------------------------------------------------------------------------
extern "C" void kernel_launch(void* const* d_in, const int* in_sizes, int n_in,
                              void* d_out, int out_size, void* d_ws, size_t ws_size,
                              hipStream_t stream) {
  const float* x = (const float*)d_in[0];
  GPtrs g;
  for (int k = 0; k < 8; ++k) g.p[k] = (const float*)d_in[k + 1];  // g1,g2,g4,g5,g7,g8,g10,g11
  f16* xT = (f16*)d_ws;                         // 26.2 MB
  f16* scratch = xT + (size_t)BB * SLICE;       // 104.9 MB

  xpose_kernel<<<BB * HH, 256, 0, stream>>>(x, xT);
  dag_kernel<<<4 * BB, NTHREADS, 0, stream>>>((const f16*)xT, g, scratch);
  reduce_kernel<<<BB * HH, 256, 0, stream>>>((const f16*)scratch, (float*)d_out);
}

// Round 3
// 288.669 us; speedup vs baseline: 2.3927x; 1.0490x over previous
//
#include <hip/hip_runtime.h>
#include <stdint.h>

#define HH 80
#define WW 80
#define CC 64
#define BB 32
#define NDIAG (HH + WW - 1)   // 159
#define SLICE (HH * WW * CC)  // 409600 f16 per (dir,b) scratch slice
#define NCW 5                 // compute waves (one 16-cell tile each)
#define NTHREADS 320          // 5 waves, all identical role

typedef _Float16 f16;
typedef _Float16 f16x8 __attribute__((ext_vector_type(8)));
typedef _Float16 f16x4 __attribute__((ext_vector_type(4)));
typedef float floatx4 __attribute__((ext_vector_type(4)));

struct GPtrs { const float* p[8]; };

// ---------------------------------------------------------------------------
// Permuted per-cell channel order ("p-order"):
//   p = quad*16 + cb*4 + r   <->   c = cb*16 + quad*4 + r
// A compute lane (quad, l15) owns channels {cb*16 + quad*4 + r : cb,r in 0..3},
// which are the 32 contiguous bytes [quad*32, quad*32+32) in p-order. This
// turns the x feed into 2xf16x8 loads and the h store into 2xf16x8 stores per
// thread (round 2 needed 4x8B each -> 2x the vmem instructions/transactions).
// ---------------------------------------------------------------------------

// Pre-pass: x[b][c][i][j] (f32) -> xP[((b*H+i)*W+j)*C + p] (f16, p-order).
__global__ __launch_bounds__(256) void xpose_kernel(const float* __restrict__ x,
                                                    f16* __restrict__ xT) {
  const int bi = blockIdx.x;            // b*HH + i
  const int b = bi / HH, i = bi - b * HH;
  __shared__ float tile[WW][CC + 1];    // [j][c], stride 65
  const float* xp = x + ((size_t)(b * CC) * HH + i) * WW;  // + c*(H*W) + j
  for (int idx = threadIdx.x; idx < CC * WW; idx += 256) {
    const int c = idx / WW, j = idx - c * WW;   // consecutive j -> coalesced reads
    tile[j][c] = xp[(size_t)c * (HH * WW) + j];
  }
  __syncthreads();
  f16* op = xT + (size_t)(b * HH + i) * WW * CC;
  for (int idx = threadIdx.x; idx < (WW * CC) / 4; idx += 256) {
    const int j = idx >> 4, m = idx & 15;       // p = m*4 + t
    const int cbase = (m & 3) * 16 + (m >> 2) * 4;  // c for (cb=m&3, quad=m>>2)
    f16x4 v;
    v[0] = (f16)tile[j][cbase + 0];
    v[1] = (f16)tile[j][cbase + 1];
    v[2] = (f16)tile[j][cbase + 2];
    v[3] = (f16)tile[j][cbase + 3];
    *(f16x4*)(op + j * CC + m * 4) = v;         // 128B contiguous per 16 lanes
  }
}

// ---------------------------------------------------------------------------
// Main kernel: 128 blocks x 320 threads (5 waves, all compute).
// Per diagonal interval, each wave:
//   - seeds MFMA C from x prefetched 2 diagonals ahead (2xf16x8 regs, p-order)
//   - reads prev-diag h from hbuf (4x ds_read_b128), two independent 2-deep
//     MFMA chains (Gv | Gh), add, relu, pack f16
//   - ds_writes h for next diag (4x b64, standard order for the B-fragment
//     reads) AND stores h to scratch in p-order (2x f16x8, fire-and-forget)
//   - issues next x prefetch LAST, then lgkmcnt(0)-only raw barrier
// LDS pipe load: 8 DS ops/wave/interval (vs 12-ish + io in the 512t design).
// Vmem: 4 instr/thread/interval, ~64 transactions/wave (vs 128 in round 2).
// ---------------------------------------------------------------------------
__global__ __launch_bounds__(NTHREADS, 1) void dag_kernel(const f16* __restrict__ xT,
                                                          GPtrs g,
                                                          f16* __restrict__ scratch) {
  const int blk = blockIdx.x;   // 0..127
  const int dir = blk >> 5;     // 0:SE 1:NE 2:NW 3:SW
  const int b   = blk & 31;
  const int tid = threadIdx.x;
  const int wv   = tid >> 6;    // 0..4
  const int lane = tid & 63;
  const int l15  = lane & 15;   // cell-in-tile (MFMA n / C-D col)
  const int quad = lane >> 4;   // k-quad / C-D row-quad
  const int cq   = quad * 4;

  const bool fi      = (dir == 1) || (dir == 2);  // flip i
  const bool fj      = (dir == 2) || (dir == 3);  // flip j
  const bool do_relu = (dir != 3);                // SW scan has no ReLU
  const float* __restrict__ gv = g.p[2 * dir];
  const float* __restrict__ gh = g.p[2 * dir + 1];

  // h state: [parity][s][c]; s=i'+1, s=0 zero guard, s=81 top guard. 144B rows.
  __align__(16) __shared__ f16 hbuf[2][HH + 2][CC + 8];   // 23,616 B

  {
    f16x8 z = {};
    f16x8* hb = (f16x8*)&hbuf[0][0][0];
    for (int idx = tid; idx < (2 * (HH + 2) * (CC + 8)) / 8; idx += NTHREADS)
      hb[idx] = z;
  }

  const f16* const xTb = xT + (size_t)b * SLICE;
  f16* const sbase = scratch + (size_t)blk * SLICE;

  // gamma A fragments: A[m][k], m = cb*16 + l15, k = half*32 + quad*8 + jj
  f16x8 Av[4][2], Ah[4][2];
#pragma unroll
  for (int cb = 0; cb < 4; ++cb) {
    const int row = cb * 16 + l15;
    const float* pv = gv + row * CC;
    const float* ph = gh + row * CC;
#pragma unroll
    for (int jj = 0; jj < 8; ++jj) {
      Av[cb][0][jj] = (f16)pv[quad * 8 + jj];
      Av[cb][1][jj] = (f16)pv[32 + quad * 8 + jj];
      Ah[cb][0][jj] = (f16)ph[quad * 8 + jj];
      Ah[cb][1][jj] = (f16)ph[32 + quad * 8 + jj];
    }
  }

  // x prefetch: lane reads its own 32B (p-order) of its cell: 2x f16x8.
  f16x8 XA[2], XB[2];
  auto prefetch = [&](int dd, f16x8 (&X)[2]) {
    const int lo2 = max(0, dd - (WW - 1));
    const int hi2 = min(dd, HH - 1);
    const int ipc = min(lo2 + wv * 16 + l15, hi2);  // clamped: dup loads benign
    const int jp2 = dd - ipc;
    const int io2 = fi ? (HH - 1 - ipc) : ipc;
    const int jo2 = fj ? (WW - 1 - jp2) : jp2;
    const f16* xp = xTb + ((io2 * WW + jo2) << 6) + quad * 16;
    X[0] = *(const f16x8*)(xp);      // p = quad*16 + 0..7   (cb 0,1)
    X[1] = *(const f16x8*)(xp + 8);  // p = quad*16 + 8..15  (cb 2,3)
  };

  prefetch(0, XA);
  prefetch(1, XB);
  __syncthreads();  // one-time full drain: hbuf zeros (+ prologue loads)

  auto step = [&](int d, int par, f16x8 (&X)[2]) {
    const int ilo = max(0, d - (WW - 1));
    const int ihi = min(d, HH - 1);
    const int ntiles = ((ihi - ilo) >> 4) + 1;
    if (wv < ntiles) {                     // wave-uniform
      const int ip  = ilo + wv * 16 + l15;
      const int ipa = min(ip, ihi);        // clamped for addresses
      const int su  = min(ip, HH + 1);     // up   (i'-1,j') -> s=i'
      const int sl  = min(ip + 1, HH + 1); // left (i',j'-1) -> s=i'+1
      const f16x8 bu0 = *(const f16x8*)&hbuf[par ^ 1][su][quad * 8];
      const f16x8 bu1 = *(const f16x8*)&hbuf[par ^ 1][su][32 + quad * 8];
      const f16x8 bl0 = *(const f16x8*)&hbuf[par ^ 1][sl][quad * 8];
      const f16x8 bl1 = *(const f16x8*)&hbuf[par ^ 1][sl][32 + quad * 8];
      const bool ok = (ip <= ihi);
      const int jp  = d - ipa;
      const int io1 = fi ? (HH - 1 - ipa) : ipa;
      const int jo1 = fj ? (WW - 1 - jp) : jp;
      f16* const so = sbase + ((io1 * WW + jo1) << 6) + quad * 16;
      f16x8 out0, out1;
#pragma unroll
      for (int cb = 0; cb < 4; ++cb) {
        const int eb = (cb & 1) * 4;
        const f16x8 xs = (cb < 2) ? X[0] : X[1];   // compile-time select
        floatx4 a1;
        a1[0] = (float)xs[eb + 0]; a1[1] = (float)xs[eb + 1];  // seed C with x
        a1[2] = (float)xs[eb + 2]; a1[3] = (float)xs[eb + 3];
        floatx4 a2 = {0.f, 0.f, 0.f, 0.f};
        // two independent 2-deep chains (Gv | Gh) -> shorter latency path
        a1 = __builtin_amdgcn_mfma_f32_16x16x32_f16(Av[cb][0], bu0, a1, 0, 0, 0);
        a2 = __builtin_amdgcn_mfma_f32_16x16x32_f16(Ah[cb][0], bl0, a2, 0, 0, 0);
        a1 = __builtin_amdgcn_mfma_f32_16x16x32_f16(Av[cb][1], bu1, a1, 0, 0, 0);
        a2 = __builtin_amdgcn_mfma_f32_16x16x32_f16(Ah[cb][1], bl1, a2, 0, 0, 0);
        float h0 = a1[0] + a2[0], h1 = a1[1] + a2[1];
        float h2 = a1[2] + a2[2], h3 = a1[3] + a2[3];
        if (do_relu) {
          h0 = fmaxf(h0, 0.f); h1 = fmaxf(h1, 0.f);
          h2 = fmaxf(h2, 0.f); h3 = fmaxf(h3, 0.f);
        }
        f16x4 hw;
        hw[0] = (f16)h0; hw[1] = (f16)h1; hw[2] = (f16)h2; hw[3] = (f16)h3;
        if (ok) *(f16x4*)&hbuf[par][ip + 1][cb * 16 + cq] = hw;  // std order
        f16x8& oo = (cb < 2) ? out0 : out1;        // p-order pack for store
        oo[eb + 0] = hw[0]; oo[eb + 1] = hw[1];
        oo[eb + 2] = hw[2]; oo[eb + 3] = hw[3];
      }
      if (ok) {                                    // fire-and-forget, 32B/lane
        *(f16x8*)(so)     = out0;
        *(f16x8*)(so + 8) = out1;
      }
    }
    // issue next prefetch LAST (unconditional: waves may activate later)
    prefetch(min(d + 2, NDIAG - 1), X);
    // Raw barrier: drain LDS only (lgkmcnt(0)); vmem stays in flight.
    __builtin_amdgcn_s_waitcnt(0xC07F);  // vmcnt(63) expcnt(7) lgkmcnt(0)
    __builtin_amdgcn_s_barrier();
  };

  for (int d = 0; d < NDIAG - 1; d += 2) {  // parity as literal -> folded addrs
    step(d, 0, XA);
    step(d + 1, 1, XB);
  }
  step(NDIAG - 1, 0, XA);  // 158 is even
}

// ---------------------------------------------------------------------------
// Reduce: out[b][c][i][j] = sum over 4 dirs of scratch[dir][b][i][j][p],
// un-permuting p -> c. For chunk k (=p/8) elems t: c = (k&1)*32 + (k>>1)*4 + t
// for t=0..3, and +16 more for t=4..7 (contiguous groups of 4 in LDS).
// ---------------------------------------------------------------------------
__global__ __launch_bounds__(256) void reduce_kernel(const f16* __restrict__ s,
                                                     float* __restrict__ out) {
  const int bi = blockIdx.x;            // b*HH + i
  const int b = bi / HH, i = bi - b * HH;
  __shared__ float tile[WW][CC + 1];    // [j][c], stride 65
  const size_t dstride = (size_t)BB * SLICE;
  const f16* p = s + (size_t)b * SLICE + (size_t)i * (WW * CC);
  for (int idx = threadIdx.x; idx < (WW * CC) / 8; idx += 256) {  // 640
    const int j = idx >> 3, k = idx & 7;
    const size_t off = (size_t)j * CC + k * 8;
    const f16x8 a0 = *(const f16x8*)(p + off);
    const f16x8 a1 = *(const f16x8*)(p + off + dstride);
    const f16x8 a2 = *(const f16x8*)(p + off + 2 * dstride);
    const f16x8 a3 = *(const f16x8*)(p + off + 3 * dstride);
    const int c0 = (k & 1) * 32 + (k >> 1) * 4;
#pragma unroll
    for (int t = 0; t < 4; ++t)
      tile[j][c0 + t] = (float)a0[t] + (float)a1[t] + (float)a2[t] + (float)a3[t];
#pragma unroll
    for (int t = 0; t < 4; ++t)
      tile[j][c0 + 16 + t] = (float)a0[4 + t] + (float)a1[4 + t]
                           + (float)a2[4 + t] + (float)a3[4 + t];
  }
  __syncthreads();
  float* op = out + ((size_t)(b * CC) * HH + i) * WW;  // + c*(H*W) + j
  const int c  = threadIdx.x >> 2;        // 0..63
  const int jb = (threadIdx.x & 3) * 4;   // 0,4,8,12
#pragma unroll
  for (int k = 0; k < 5; ++k) {
    const int j0 = jb + k * 16;
    floatx4 v;
    v[0] = tile[j0 + 0][c];
    v[1] = tile[j0 + 1][c];
    v[2] = tile[j0 + 2][c];
    v[3] = tile[j0 + 3][c];
    *(floatx4*)(op + (size_t)c * (HH * WW) + j0) = v;  // 64B contiguous per 4 lanes
  }
}

// ---------------------------------------------------------------------------
extern "C" void kernel_launch(void* const* d_in, const int* in_sizes, int n_in,
                              void* d_out, int out_size, void* d_ws, size_t ws_size,
                              hipStream_t stream) {
  const float* x = (const float*)d_in[0];
  GPtrs g;
  for (int k = 0; k < 8; ++k) g.p[k] = (const float*)d_in[k + 1];  // g1,g2,g4,g5,g7,g8,g10,g11
  f16* xT = (f16*)d_ws;                         // 26.2 MB
  f16* scratch = xT + (size_t)BB * SLICE;       // 104.9 MB

  xpose_kernel<<<BB * HH, 256, 0, stream>>>(x, xT);
  dag_kernel<<<4 * BB, NTHREADS, 0, stream>>>((const f16*)xT, g, scratch);
  reduce_kernel<<<BB * HH, 256, 0, stream>>>((const f16*)scratch, (float*)d_out);
}

// Round 4
// 282.234 us; speedup vs baseline: 2.4472x; 1.0228x over previous
//
#include <hip/hip_runtime.h>
#include <stdint.h>

#define HH 80
#define WW 80
#define CC 64
#define BB 32
#define NDIAG (HH + WW - 1)   // 159
#define SLICE (HH * WW * CC)  // 409600 f16 per (dir,b) scratch slice
#define NCW 5                 // compute waves (one 16-cell tile each)
#define NTHREADS 512          // 5 compute + 3 io waves

typedef _Float16 f16;
typedef _Float16 f16x8 __attribute__((ext_vector_type(8)));
typedef _Float16 f16x4 __attribute__((ext_vector_type(4)));
typedef float floatx4 __attribute__((ext_vector_type(4)));

struct GPtrs { const float* p[8]; };

// ---------------------------------------------------------------------------
// x pre-pass writes "p-order": p = quad*16 + cb*4 + r  <->  c = cb*16 + quad*4 + r.
// A compute lane (quad,l15) then reads its 16 seed channels as ONE 32B run
// (2x f16x8 loads). Scratch/h stay in standard channel order.
// ---------------------------------------------------------------------------
__global__ __launch_bounds__(256) void xpose_kernel(const float* __restrict__ x,
                                                    f16* __restrict__ xT) {
  const int bi = blockIdx.x;            // b*HH + i
  const int b = bi / HH, i = bi - b * HH;
  __shared__ float tile[WW][CC + 1];    // [j][c], stride 65
  const float* xp = x + ((size_t)(b * CC) * HH + i) * WW;  // + c*(H*W) + j
  for (int idx = threadIdx.x; idx < CC * WW; idx += 256) {
    const int c = idx / WW, j = idx - c * WW;   // consecutive j -> coalesced reads
    tile[j][c] = xp[(size_t)c * (HH * WW) + j];
  }
  __syncthreads();
  f16* op = xT + (size_t)(b * HH + i) * WW * CC;
  for (int idx = threadIdx.x; idx < (WW * CC) / 4; idx += 256) {
    const int j = idx >> 4, m = idx & 15;       // p = m*4 + t
    const int cbase = (m & 3) * 16 + (m >> 2) * 4;  // c for (cb=m&3, quad=m>>2)
    f16x4 v;
    v[0] = (f16)tile[j][cbase + 0];
    v[1] = (f16)tile[j][cbase + 1];
    v[2] = (f16)tile[j][cbase + 2];
    v[3] = (f16)tile[j][cbase + 3];
    *(f16x4*)(op + j * CC + m * 4) = v;         // 128B contiguous per 16 lanes
  }
}

// ---------------------------------------------------------------------------
// Main kernel: 128 blocks x 512 threads. HYBRID role split:
//   waves 0..4 (compute): x self-prefetched 2 diagonals ahead in REGISTERS
//     (2 loads/thread, no store-data hazard since XA/XB alternate) + 8 LDS ops
//     (4x b128 hbuf read, 4x b64 hbuf write) + 16 MFMA. ZERO vmem stores --
//     the round-3 counters showed each vmem instr on the barrier path costs
//     ~60cy (store-data register hazard forces vmcnt waits).
//   waves 5..7 (io): flush diag d-1's h from hbuf[q] (read-only during
//     interval d) to scratch. 4x b128 LDS read + 4x dwordx4 store. All store
//     latency lives here, off the compute critical path.
// Barrier: lgkmcnt(0)-only, uniform control flow; vmem stays in flight.
// ---------------------------------------------------------------------------
__global__ __launch_bounds__(NTHREADS, 1) void dag_kernel(const f16* __restrict__ xT,
                                                          GPtrs g,
                                                          f16* __restrict__ scratch) {
  const int blk = blockIdx.x;   // 0..127
  const int dir = blk >> 5;     // 0:SE 1:NE 2:NW 3:SW
  const int b   = blk & 31;
  const int tid = threadIdx.x;
  const int wv   = tid >> 6;    // 0..7
  const int lane = tid & 63;
  const int l15  = lane & 15;   // compute: cell-in-tile (MFMA n / C-D col)
  const int quad = lane >> 4;   // compute: k-quad / C-D row-quad
  const int cq   = quad * 4;

  const bool fi      = (dir == 1) || (dir == 2);  // flip i
  const bool fj      = (dir == 2) || (dir == 3);  // flip j
  const bool do_relu = (dir != 3);                // SW scan has no ReLU
  const float* __restrict__ gv = g.p[2 * dir];
  const float* __restrict__ gh = g.p[2 * dir + 1];

  // h state: [parity][s][c]; s=i'+1, s=0 zero guard, s=81 top guard. 144B rows.
  __align__(16) __shared__ f16 hbuf[2][HH + 2][CC + 8];   // 23,616 B

  {
    f16x8 z = {};
    f16x8* hb = (f16x8*)&hbuf[0][0][0];
    for (int idx = tid; idx < (2 * (HH + 2) * (CC + 8)) / 8; idx += NTHREADS)
      hb[idx] = z;
  }

  const f16* const xTb = xT + (size_t)b * SLICE;
  f16* const sbase = scratch + (size_t)blk * SLICE;

  // global cell offset (units of CC elems) of cell index `cell` on diag dd,
  // clamped into dd's valid range (clamped duplicates are benign). io use.
  auto cellOff = [&](int dd, int cell) -> int {
    const int lo = max(0, dd - (WW - 1));
    const int hi = min(dd, HH - 1);
    const int ipc = min(max(cell, lo), hi);
    const int jp = dd - ipc;
    const int io1 = fi ? (HH - 1 - ipc) : ipc;
    const int jo1 = fj ? (WW - 1 - jp) : jp;
    return io1 * WW + jo1;
  };

  // ---- per-role persistent state (uniform scope) ----
  f16x8 Av[4][2], Ah[4][2];     // compute: gamma A-fragments
  f16x8 XA[2], XB[2];           // compute: x seeds (p-order), depth-2 prefetch
  int ucell[4];                 // io: cell index per chunk
  const int cm = lane >> 3;     // io: cell-in-chunk 0..7
  const int c8 = (lane & 7) * 8;// io: channel offset

  // x prefetch: lane reads its own 32B (p-order) of its cell: 2x f16x8.
  auto prefetch = [&](int dd, f16x8 (&X)[2]) {
    const int lo2 = max(0, dd - (WW - 1));
    const int hi2 = min(dd, HH - 1);
    const int ipc = min(lo2 + wv * 16 + l15, hi2);  // clamped: dup loads benign
    const int jp2 = dd - ipc;
    const int io2 = fi ? (HH - 1 - ipc) : ipc;
    const int jo2 = fj ? (WW - 1 - jp2) : jp2;
    const f16* xp = xTb + ((io2 * WW + jo2) << 6) + quad * 16;
    X[0] = *(const f16x8*)(xp);      // p = quad*16 + 0..7   (cb 0,1)
    X[1] = *(const f16x8*)(xp + 8);  // p = quad*16 + 8..15  (cb 2,3)
  };

  if (wv < NCW) {
    // compute wave: load A fragments. A[m][k]: m=l15, k=quad*8+jj.
#pragma unroll
    for (int cb = 0; cb < 4; ++cb) {
      const int row = cb * 16 + l15;
      const float* pv = gv + row * CC;
      const float* ph = gh + row * CC;
#pragma unroll
      for (int jj = 0; jj < 8; ++jj) {
        Av[cb][0][jj] = (f16)pv[quad * 8 + jj];
        Av[cb][1][jj] = (f16)pv[32 + quad * 8 + jj];
        Ah[cb][0][jj] = (f16)ph[quad * 8 + jj];
        Ah[cb][1][jj] = (f16)ph[32 + quad * 8 + jj];
      }
    }
    prefetch(0, XA);
    prefetch(1, XB);
  } else {
    // io wave: chunk assignment (10 chunks of 8 cells; chunk 9 duplicated
    // across waves -- benign: same data, same destination).
    const int wio = wv - NCW;   // 0..2
#pragma unroll
    for (int k = 0; k < 4; ++k) ucell[k] = min(wio + 3 * k, 9) * 8 + cm;
  }

  __syncthreads();  // zero-init visible; one-time full drain

  auto step = [&](int d, int par, f16x8 (&X)[2]) {
    if (wv < NCW) {
      // ---------------- compute wave: LDS + MFMA + x prefetch ----------------
      const int ilo = max(0, d - (WW - 1));
      const int ihi = min(d, HH - 1);
      const int ntiles = ((ihi - ilo) >> 4) + 1;
      if (wv < ntiles) {                     // wave-uniform
        const int ip  = ilo + wv * 16 + l15;
        const int su  = min(ip, HH + 1);     // up   (i'-1,j') -> s=i'
        const int sl  = min(ip + 1, HH + 1); // left (i',j'-1) -> s=i'+1
        const f16x8 bu0 = *(const f16x8*)&hbuf[par ^ 1][su][quad * 8];
        const f16x8 bu1 = *(const f16x8*)&hbuf[par ^ 1][su][32 + quad * 8];
        const f16x8 bl0 = *(const f16x8*)&hbuf[par ^ 1][sl][quad * 8];
        const f16x8 bl1 = *(const f16x8*)&hbuf[par ^ 1][sl][32 + quad * 8];
        const bool ok = (ip <= ihi);
#pragma unroll
        for (int cb = 0; cb < 4; ++cb) {
          const int eb = (cb & 1) * 4;
          const f16x8 xs = (cb < 2) ? X[0] : X[1];   // compile-time select
          floatx4 a1;
          a1[0] = (float)xs[eb + 0]; a1[1] = (float)xs[eb + 1];  // seed C = x
          a1[2] = (float)xs[eb + 2]; a1[3] = (float)xs[eb + 3];
          floatx4 a2 = {0.f, 0.f, 0.f, 0.f};
          // two independent 2-deep chains (Gv | Gh)
          a1 = __builtin_amdgcn_mfma_f32_16x16x32_f16(Av[cb][0], bu0, a1, 0, 0, 0);
          a2 = __builtin_amdgcn_mfma_f32_16x16x32_f16(Ah[cb][0], bl0, a2, 0, 0, 0);
          a1 = __builtin_amdgcn_mfma_f32_16x16x32_f16(Av[cb][1], bu1, a1, 0, 0, 0);
          a2 = __builtin_amdgcn_mfma_f32_16x16x32_f16(Ah[cb][1], bl1, a2, 0, 0, 0);
          float h0 = a1[0] + a2[0], h1 = a1[1] + a2[1];
          float h2 = a1[2] + a2[2], h3 = a1[3] + a2[3];
          if (do_relu) {
            h0 = fmaxf(h0, 0.f); h1 = fmaxf(h1, 0.f);
            h2 = fmaxf(h2, 0.f); h3 = fmaxf(h3, 0.f);
          }
          f16x4 hw;
          hw[0] = (f16)h0; hw[1] = (f16)h1; hw[2] = (f16)h2; hw[3] = (f16)h3;
          if (ok) *(f16x4*)&hbuf[par][ip + 1][cb * 16 + cq] = hw;
        }
      }
      // issue next prefetch LAST (loads only; consumed at step d+2)
      prefetch(min(d + 2, NDIAG - 1), X);
    } else {
      // ---------------- io wave: flush diag d-1 h to scratch ----------------
      if (d >= 1) {
        const int dF = d - 1;
        const int q  = par ^ 1;              // hbuf[q] holds diag dF, read-only now
        const int lo = max(0, dF - (WW - 1)), hi = min(dF, HH - 1);
#pragma unroll
        for (int k = 0; k < 4; ++k) {
          const int ipc = min(max(ucell[k], lo), hi);
          const f16x8 hv = *(const f16x8*)&hbuf[q][ipc + 1][c8];
          *(f16x8*)(sbase + (cellOff(dF, ucell[k]) << 6) + c8) = hv;
        }
      }
    }
    // Raw barrier: drain LDS only (lgkmcnt(0)); vmem stays in flight.
    __builtin_amdgcn_s_waitcnt(0xC07F);  // vmcnt(63) expcnt(7) lgkmcnt(0)
    __builtin_amdgcn_s_barrier();
  };

  for (int d = 0; d < NDIAG - 1; d += 2) {  // parity as literal -> folded addrs
    step(d, 0, XA);
    step(d + 1, 1, XB);
  }
  step(NDIAG - 1, 0, XA);  // 158 is even

  // final flush: diag NDIAG-1 (parity (NDIAG-1)&1 = 0)
  if (wv >= NCW) {
    const int dF = NDIAG - 1;
    const int lo = max(0, dF - (WW - 1)), hi = min(dF, HH - 1);
#pragma unroll
    for (int k = 0; k < 4; ++k) {
      const int ipc = min(max(ucell[k], lo), hi);
      const f16x8 hv = *(const f16x8*)&hbuf[dF & 1][ipc + 1][c8];
      *(f16x8*)(sbase + (cellOff(dF, ucell[k]) << 6) + c8) = hv;
    }
  }
}

// ---------------------------------------------------------------------------
// Reduce: out[b][c][i][j] = sum over 4 dirs of scratch[dir][b][i][j][c].
// Scratch is standard channel order.
// ---------------------------------------------------------------------------
__global__ __launch_bounds__(256) void reduce_kernel(const f16* __restrict__ s,
                                                     float* __restrict__ out) {
  const int bi = blockIdx.x;            // b*HH + i
  const int b = bi / HH, i = bi - b * HH;
  __shared__ float tile[WW][CC + 1];    // [j][c], stride 65
  const size_t dstride = (size_t)BB * SLICE;
  const f16* p = s + (size_t)b * SLICE + (size_t)i * (WW * CC);
  for (int idx = threadIdx.x; idx < (WW * CC) / 8; idx += 256) {  // 640
    const int j = idx >> 3, c8 = (idx & 7) * 8;
    const size_t off = (size_t)j * CC + c8;
    const f16x8 a0 = *(const f16x8*)(p + off);
    const f16x8 a1 = *(const f16x8*)(p + off + dstride);
    const f16x8 a2 = *(const f16x8*)(p + off + 2 * dstride);
    const f16x8 a3 = *(const f16x8*)(p + off + 3 * dstride);
#pragma unroll
    for (int k = 0; k < 8; ++k)
      tile[j][c8 + k] = (float)a0[k] + (float)a1[k] + (float)a2[k] + (float)a3[k];
  }
  __syncthreads();
  float* op = out + ((size_t)(b * CC) * HH + i) * WW;  // + c*(H*W) + j
  const int c  = threadIdx.x >> 2;        // 0..63
  const int jb = (threadIdx.x & 3) * 4;   // 0,4,8,12
#pragma unroll
  for (int k = 0; k < 5; ++k) {
    const int j0 = jb + k * 16;
    floatx4 v;
    v[0] = tile[j0 + 0][c];
    v[1] = tile[j0 + 1][c];
    v[2] = tile[j0 + 2][c];
    v[3] = tile[j0 + 3][c];
    *(floatx4*)(op + (size_t)c * (HH * WW) + j0) = v;  // 64B contiguous per 4 lanes
  }
}

// ---------------------------------------------------------------------------
extern "C" void kernel_launch(void* const* d_in, const int* in_sizes, int n_in,
                              void* d_out, int out_size, void* d_ws, size_t ws_size,
                              hipStream_t stream) {
  const float* x = (const float*)d_in[0];
  GPtrs g;
  for (int k = 0; k < 8; ++k) g.p[k] = (const float*)d_in[k + 1];  // g1,g2,g4,g5,g7,g8,g10,g11
  f16* xT = (f16*)d_ws;                         // 26.2 MB
  f16* scratch = xT + (size_t)BB * SLICE;       // 104.9 MB

  xpose_kernel<<<BB * HH, 256, 0, stream>>>(x, xT);
  dag_kernel<<<4 * BB, NTHREADS, 0, stream>>>((const f16*)xT, g, scratch);
  reduce_kernel<<<BB * HH, 256, 0, stream>>>((const f16*)scratch, (float*)d_out);
}